// Round 11
// baseline (81.446 us; speedup 1.0000x reference)
//
#include <hip/hip_runtime.h>

#define N_TOTAL   16777216
#define NWIN      65536
#define MIN_FREQS 202
#define MIN_TIMES 51773
#define NSLOTS    64
#define NBLK      512      /* k_stats grid: 512 blocks x 8 waves, 4 iters/wave */

/* workspace layout (float indices) */
#define IDX_TCNT    2      /* int: time-mask popcount (atomicAdd, 64 ops) */
#define IDX_FMALL   3      /* int: 1 = freq mask all ones */
#define IDX_TTHR    4
#define IDX_INVNORM 5
#define IDX_FCNT    6
#define IDX_FMASK   8      /* 256 floats, NATURAL frequency order */
#define IDX_SLOTS   264    /* 64*256 floats, freq-energy partial slots */
#define IDX_AMAXB   16648  /* per-block abs-max (plain stores) */
#define IDX_TMAXB   18696  /* per-block time-energy max */
#define IDX_SUMSQ   20744  /* 65536 floats, per-window spectral energy */
#define IDX_TMASKA  86280  /* 65536 floats, time mask */

/* exact 16-lane (DPP row) sum: 4 VALU adds, no LDS pipe */
__device__ __forceinline__ float dpp_row_sum16(float x)
{
    x += __int_as_float(__builtin_amdgcn_mov_dpp(__float_as_int(x), 0xB1,  0xF, 0xF, true)); /* quad_perm [1,0,3,2] */
    x += __int_as_float(__builtin_amdgcn_mov_dpp(__float_as_int(x), 0x4E,  0xF, 0xF, true)); /* quad_perm [2,3,0,1] */
    x += __int_as_float(__builtin_amdgcn_mov_dpp(__float_as_int(x), 0x141, 0xF, 0xF, true)); /* row_half_mirror */
    x += __int_as_float(__builtin_amdgcn_mov_dpp(__float_as_int(x), 0x140, 0xF, 0xF, true)); /* row_mirror */
    return x;
}

/* in-register 16-point FFT, natural in -> natural out (DIT, brev first). */
__device__ __forceinline__ void fft16(float ar[16], float ai[16])
{
#define SWP(a,b) { float t_=ar[a]; ar[a]=ar[b]; ar[b]=t_; \
                   t_=ai[a]; ai[a]=ai[b]; ai[b]=t_; }
    SWP(1,8) SWP(2,4) SWP(3,12) SWP(5,10) SWP(7,14) SWP(11,13)
#undef SWP
#pragma unroll
    for (int i = 0; i < 16; i += 2) {
        float tr = ar[i+1], ti = ai[i+1];
        ar[i+1] = ar[i] - tr; ai[i+1] = ai[i] - ti;
        ar[i] += tr;          ai[i] += ti;
    }
#pragma unroll
    for (int i = 0; i < 16; i += 4) {
        { float tr = ar[i+2], ti = ai[i+2];
          ar[i+2] = ar[i] - tr; ai[i+2] = ai[i] - ti; ar[i] += tr; ai[i] += ti; }
        { float tr = ai[i+3], ti = -ar[i+3];
          ar[i+3] = ar[i+1] - tr; ai[i+3] = ai[i+1] - ti; ar[i+1] += tr; ai[i+1] += ti; }
    }
#pragma unroll
    for (int i = 0; i < 16; i += 8) {
        { float tr = ar[i+4], ti = ai[i+4];
          ar[i+4] = ar[i] - tr; ai[i+4] = ai[i] - ti; ar[i] += tr; ai[i] += ti; }
        { float br = ar[i+5], bi = ai[i+5];
          float tr = 0.70710678f * (br + bi), ti = 0.70710678f * (bi - br);
          ar[i+5] = ar[i+1] - tr; ai[i+5] = ai[i+1] - ti; ar[i+1] += tr; ai[i+1] += ti; }
        { float tr = ai[i+6], ti = -ar[i+6];
          ar[i+6] = ar[i+2] - tr; ai[i+6] = ai[i+2] - ti; ar[i+2] += tr; ai[i+2] += ti; }
        { float br = ar[i+7], bi = ai[i+7];
          float tr = 0.70710678f * (bi - br), ti = -0.70710678f * (br + bi);
          ar[i+7] = ar[i+3] - tr; ai[i+7] = ai[i+3] - ti; ar[i+3] += tr; ai[i+3] += ti; }
    }
    { float tr = ar[8], ti = ai[8];
      ar[8] = ar[0] - tr; ai[8] = ai[0] - ti; ar[0] += tr; ai[0] += ti; }
#define BUT(J, WR, WI) { float br = ar[8+J], bi = ai[8+J];     \
      float tr = br*(WR) - bi*(WI), ti = br*(WI) + bi*(WR);    \
      ar[8+J] = ar[J] - tr; ai[8+J] = ai[J] - ti; ar[J] += tr; ai[J] += ti; }
    BUT(1,  0.92387953f, -0.38268343f)
    BUT(2,  0.70710678f, -0.70710678f)
    BUT(3,  0.38268343f, -0.92387953f)
    BUT(4,  0.f, -1.f)
    BUT(5, -0.38268343f, -0.92387953f)
    BUT(6, -0.70710678f, -0.70710678f)
    BUT(7, -0.92387953f, -0.38268343f)
#undef BUT
}

/* ---- K1: 16x16 four-step FFT; 512-thread blocks (8 waves) to raise
   waves/CU 16->24 at unchanged 4 iters/wave (75% prefetch coverage). ------- */
__global__ __launch_bounds__(512) void k_stats(const float* __restrict__ x,
                                               float* __restrict__ W)
{
    __shared__ float B[32][272];   /* 8 waves x 4 windows: 34,816 B */
    __shared__ float sE[256];
    __shared__ float red[512];
    const int tid  = threadIdx.x;
    const int lane = tid & 63;
    const int wv   = tid >> 6;          /* 0..7 */
    const int subw = lane >> 4;
    const int n2   = lane & 15;
    float* Bs = B[wv * 4 + subw];

    float cs, sn;                       /* W256^{n2} */
    __sincosf(-0.024543692606170f * (float)n2, &sn, &cs);

    float e[16];
#pragma unroll
    for (int k = 0; k < 16; ++k) e[k] = 0.f;
    float amax = 0.f, tmx = 0.f;
    float* sumsq = W + IDX_SUMSQ;

    const int wave_gid = (blockIdx.x << 3) | wv;     /* 0..4095 */
    const int GSTRIDE  = 8 * NBLK;                   /* 4096 */

    /* prologue: load iteration 0 */
    const float4* xg = (const float4*)(x + (size_t)wave_gid * 1024);
    float4 v0 = xg[lane];
    float4 v1 = xg[64 + lane];
    float4 v2 = xg[128 + lane];
    float4 v3 = xg[192 + lane];

#pragma unroll 1
    for (int g = wave_gid; g < NWIN / 4; g += GSTRIDE) {
        /* 1. stage current iteration into this wave's LDS */
        *(float4*)&B[wv * 4 + 0][lane * 4] = v0;
        *(float4*)&B[wv * 4 + 1][lane * 4] = v1;
        *(float4*)&B[wv * 4 + 2][lane * 4] = v2;
        *(float4*)&B[wv * 4 + 3][lane * 4] = v3;
        /* 2. abs-max from registers (before prefetch overwrites) */
        amax = fmaxf(amax, fmaxf(fmaxf(fabsf(v0.x), fabsf(v0.y)),
                                 fmaxf(fabsf(v0.z), fabsf(v0.w))));
        amax = fmaxf(amax, fmaxf(fmaxf(fabsf(v1.x), fabsf(v1.y)),
                                 fmaxf(fabsf(v1.z), fabsf(v1.w))));
        amax = fmaxf(amax, fmaxf(fmaxf(fabsf(v2.x), fabsf(v2.y)),
                                 fmaxf(fabsf(v2.z), fabsf(v2.w))));
        amax = fmaxf(amax, fmaxf(fmaxf(fabsf(v3.x), fabsf(v3.y)),
                                 fmaxf(fabsf(v3.z), fabsf(v3.w))));
        /* 3. prefetch next iteration (lands under the FFT below) */
        const int gn = g + GSTRIDE;
        if (gn < NWIN / 4) {
            const float4* xn = (const float4*)(x + (size_t)gn * 1024);
            v0 = xn[lane];
            v1 = xn[64 + lane];
            v2 = xn[128 + lane];
            v3 = xn[192 + lane];
        }
        /* 4. column read (in-order DS pipe: no runtime wait needed) */
        asm volatile("" ::: "memory");
        float ar[16], ai[16];
#pragma unroll
        for (int j = 0; j < 16; ++j) { ar[j] = Bs[16 * j + n2]; ai[j] = 0.f; }

        fft16(ar, ai);                       /* FFT over n1 (intra-lane) */

        /* twiddle W256^{n2*k1} via recurrence */
        { float wr = 1.f, wi = 0.f;
#pragma unroll
          for (int k = 1; k < 16; ++k) {
              const float nwr = wr * cs - wi * sn;
              const float nwi = wr * sn + wi * cs;
              wr = nwr; wi = nwi;
              const float xr = ar[k], xi = ai[k];
              ar[k] = xr * wr - xi * wi;
              ai[k] = xr * wi + xi * wr;
          } }

        /* 5. 16x16 transpose, sequential re/im b32 planes, stride 17 (0-conflict) */
        asm volatile("" ::: "memory");
#pragma unroll
        for (int k = 0; k < 16; ++k) Bs[17 * k + n2] = ar[k];
        asm volatile("" ::: "memory");
#pragma unroll
        for (int k = 0; k < 16; ++k) ar[k] = Bs[17 * n2 + k];
        asm volatile("" ::: "memory");
#pragma unroll
        for (int k = 0; k < 16; ++k) Bs[17 * k + n2] = ai[k];
        asm volatile("" ::: "memory");
#pragma unroll
        for (int k = 0; k < 16; ++k) ai[k] = Bs[17 * n2 + k];

        fft16(ar, ai);                       /* FFT over n2 -> X[16k2 + n2] */

        float p = 0.f;
#pragma unroll
        for (int k = 0; k < 16; ++k) {
            const float t = fmaf(ar[k], ar[k], ai[k] * ai[k]);
            e[k] += t; p += t;
        }
        /* per-window spectral energy (= 256*sumsq by Parseval; scale-free) */
        p = dpp_row_sum16(p);
        if (n2 == 0) sumsq[g * 4 + subw] = p;
        tmx = fmaxf(tmx, p);
    }

    /* block-combine freq energies (bin = 16*k2 + n2) -> distributed slots */
    if (tid < 256) sE[tid] = 0.f;
    __syncthreads();
#pragma unroll
    for (int k = 0; k < 16; ++k)
        atomicAdd(&sE[k * 16 + n2], e[k]);
    __syncthreads();
    if (tid < 256)
        atomicAdd(&W[IDX_SLOTS + (size_t)(blockIdx.x & (NSLOTS - 1)) * 256 + tid], sE[tid]);

    /* block tree-reduce amax / tmx -> PLAIN per-block stores */
    red[tid] = amax; __syncthreads();
    for (int s = 256; s > 0; s >>= 1) {
        if (tid < s) red[tid] = fmaxf(red[tid], red[tid + s]);
        __syncthreads();
    }
    if (tid == 0) W[IDX_AMAXB + blockIdx.x] = red[0];
    __syncthreads();
    red[tid] = tmx; __syncthreads();
    for (int s = 256; s > 0; s >>= 1) {
        if (tid < s) red[tid] = fmaxf(red[tid], red[tid + s]);
        __syncthreads();
    }
    if (tid == 0) W[IDX_TMAXB + blockIdx.x] = red[0];
}

/* ---------------- K2: merged masks pass ------------------------------------
   block 0      : freq mask + flags + invnorm
   blocks 1..64 : time threshold mask + count (tthr recomputed locally) ------ */
__global__ __launch_bounds__(256) void k_post(float* __restrict__ W)
{
    __shared__ float red[256];
    const int tid = threadIdx.x;

    if (blockIdx.x != 0) {
        /* local tmax reduce (2KB redundant read per block — cheap) */
        float tm = 0.f;
#pragma unroll
        for (int k = 0; k < NBLK / 256; ++k)
            tm = fmaxf(tm, W[IDX_TMAXB + k * 256 + tid]);
        red[tid] = tm; __syncthreads();
        for (int s = 128; s > 0; s >>= 1) {
            if (tid < s) red[tid] = fmaxf(red[tid], red[tid + s]);
            __syncthreads();
        }
        const float tthr = 0.05f * red[0];
        __syncthreads();
        const float* sumsq = W + IDX_SUMSQ;
        float* tmask = W + IDX_TMASKA;
        const int base = (blockIdx.x - 1) * 1024 + tid;
        int c = 0;
#pragma unroll
        for (int k = 0; k < 4; k++) {
            const int i = base + k * 256;
            const int mm = (sumsq[i] > tthr) ? 1 : 0;
            c += mm;
            tmask[i] = (float)mm;
        }
        red[tid] = (float)c; __syncthreads();
        for (int s = 128; s > 0; s >>= 1) {
            if (tid < s) red[tid] += red[tid + s];
            __syncthreads();
        }
        if (tid == 0) atomicAdd((int*)W + IDX_TCNT, (int)red[0]);
        return;
    }

    /* ---- block 0: freq mask / flags / norm ---- */
    __shared__ float e[256];
    float am = 0.f;
#pragma unroll
    for (int k = 0; k < NBLK / 256; ++k)
        am = fmaxf(am, W[IDX_AMAXB + k * 256 + tid]);
    red[tid] = am; __syncthreads();
    for (int s = 128; s > 0; s >>= 1) {
        if (tid < s) red[tid] = fmaxf(red[tid], red[tid + s]);
        __syncthreads();
    }
    const float amax = red[0];
    __syncthreads();

    float acc = 0.f;
#pragma unroll
    for (int s = 0; s < NSLOTS; s++) acc += W[IDX_SLOTS + s * 256 + tid];
    e[tid] = acc;
    red[tid] = acc; __syncthreads();
    for (int s = 128; s > 0; s >>= 1) {
        if (tid < s) red[tid] = fmaxf(red[tid], red[tid + s]);
        __syncthreads();
    }
    const float fthr = 0.05f * red[0];
    __syncthreads();
    const int my = (acc > fthr) ? 1 : 0;
    red[tid] = (float)my; __syncthreads();
    for (int s = 128; s > 0; s >>= 1) {
        if (tid < s) red[tid] += red[tid + s];
        __syncthreads();
    }
    const int fcnt = (int)red[0];
    __syncthreads();
    float m;
    if (fcnt >= MIN_FREQS) {
        m = (float)my;
    } else {
        /* exact top-k; NATURAL order, ties by lower index */
        int rank = 0;
        for (int j = 0; j < 256; j++) {
            const float ej = e[j];
            if (ej > acc || (ej == acc && j < tid)) rank++;
        }
        m = (rank < MIN_FREQS) ? 1.f : 0.f;
    }
    W[IDX_FMASK + tid] = m;
    red[tid] = m; __syncthreads();
    for (int s = 128; s > 0; s >>= 1) {
        if (tid < s) red[tid] += red[tid + s];
        __syncthreads();
    }
    if (tid == 0) {
        ((int*)W)[IDX_FMALL] = ((int)red[0] == 256) ? 1 : 0;
        ((int*)W)[IDX_FCNT]  = fcnt;
        W[IDX_INVNORM] = 1.f / ((amax > 1e-10f) ? amax : 1.f);
    }
}

/* ---------------- K2b: exact time top-k fallback (early-exit normally) ----- */
__global__ __launch_bounds__(256) void k_timefb(float* __restrict__ W)
{
    if (((const int*)W)[IDX_TCNT] >= MIN_TIMES) return;
    const int t = blockIdx.x * 256 + threadIdx.x;
    const float* sumsq = W + IDX_SUMSQ;
    const float st = sumsq[t];
    int rank = 0;
    for (int j = 0; j < NWIN; j++) {
        const float sj = sumsq[j];
        if (sj > st || (sj == st && j < t)) rank++;
    }
    W[IDX_TMASKA + t] = (rank < MIN_TIMES) ? 1.f : 0.f;
}

/* ---------------- K3: output pass ------------------------------------------ */
__global__ __launch_bounds__(256) void k_out(const float* __restrict__ x,
                                             float* __restrict__ out,
                                             const float* __restrict__ W)
{
    const int tid = threadIdx.x;
    const int fm_all = ((const int*)W)[IDX_FMALL];
    const float inv_norm = W[IDX_INVNORM];
    if (fm_all) {
        /* ifft(fft(x) * 1) == x : masked scaled copy, float4 */
        const float4* xi = (const float4*)x;
        float4* yo = (float4*)out;
        const float* tmask = W + IDX_TMASKA;
        for (int i = blockIdx.x * 256 + tid; i < N_TOTAL / 4; i += gridDim.x * 256) {
            const float s = inv_norm * tmask[i >> 6];
            float4 v = xi[i];
            v.x *= s; v.y *= s; v.z *= s; v.w *= s;
            yo[i] = v;
        }
        return;
    }
    /* general path: FFT -> freq mask -> IFFT per window (LDS, correctness path).
       DIF storage order is bit-reversed: mask lookup uses brev(tid). */
    __shared__ float re[256], im[256], twr[128], twi[128], fm[256];
    if (tid < 128) {
        float s, c;
        __sincosf(-6.283185307179586f * (float)tid / 256.0f, &s, &c);
        twr[tid] = c; twi[tid] = s;
    }
    fm[tid] = W[IDX_FMASK + (int)(__brev((unsigned)tid) >> 24)];
    __syncthreads();
    const float scale = inv_norm * (1.f / 256.f);
    for (int w = blockIdx.x; w < NWIN; w += gridDim.x) {
        const float tm = W[IDX_TMASKA + w];
        if (tm == 0.f) { out[w * 256 + tid] = 0.f; continue; }
        re[tid] = x[w * 256 + tid]; im[tid] = 0.f;
        __syncthreads();
        for (int lh = 7; lh >= 0; lh--) {              /* DIF forward */
            const int half = 1 << lh;
            if (tid < 128) {
                const int k  = tid & (half - 1);
                const int i0 = ((tid & ~(half - 1)) << 1) | k;
                const int i1 = i0 + half;
                const float ar = re[i0], ai = im[i0], br = re[i1], bi = im[i1];
                const float dr = ar - br, di = ai - bi;
                re[i0] = ar + br; im[i0] = ai + bi;
                const int ti = k << (7 - lh);
                const float wr = twr[ti], wi = twi[ti];
                re[i1] = dr * wr - di * wi;
                im[i1] = dr * wi + di * wr;
            }
            __syncthreads();
        }
        re[tid] *= fm[tid]; im[tid] *= fm[tid];
        __syncthreads();
        for (int lh = 0; lh < 8; lh++) {               /* DIT inverse (conj) */
            const int half = 1 << lh;
            if (tid < 128) {
                const int k  = tid & (half - 1);
                const int i0 = ((tid & ~(half - 1)) << 1) | k;
                const int i1 = i0 + half;
                const int ti = k << (7 - lh);
                const float wr = twr[ti], wi = -twi[ti];
                const float br = re[i1], bi = im[i1];
                const float tr = br * wr - bi * wi;
                const float ts = br * wi + bi * wr;
                const float ar = re[i0], ai = im[i0];
                re[i1] = ar - tr; im[i1] = ai - ts;
                re[i0] = ar + tr; im[i0] = ai + ts;
            }
            __syncthreads();
        }
        out[w * 256 + tid] = re[tid] * scale;
        __syncthreads();
    }
}

extern "C" void kernel_launch(void* const* d_in, const int* in_sizes, int n_in,
                              void* d_out, int out_size, void* d_ws, size_t ws_size,
                              hipStream_t stream)
{
    const float* x = (const float*)d_in[0];
    float* out = (float*)d_out;
    float* W = (float*)d_ws;
    /* zero flags + freq slots */
    hipMemsetAsync(d_ws, 0, (size_t)IDX_AMAXB * sizeof(float), stream);
    hipLaunchKernelGGL(k_stats,  dim3(NBLK), dim3(512), 0, stream, x, W);
    hipLaunchKernelGGL(k_post,   dim3(65),   dim3(256), 0, stream, W);
    hipLaunchKernelGGL(k_timefb, dim3(256),  dim3(256), 0, stream, W);
    hipLaunchKernelGGL(k_out,    dim3(2048), dim3(256), 0, stream, x, out, W);
}

// Round 12
// 67.878 us; speedup vs baseline: 1.1999x; 1.1999x over previous
//
#include <hip/hip_runtime.h>

#define N_TOTAL   16777216
#define NWIN      65536
#define MIN_FREQS 202
#define MIN_TIMES 51773
#define NSLOTS    64
#define NBLK      256      /* k_stats grid: 1 block/CU, 256 windows each */

/* workspace layout (float indices) */
#define IDX_TCNT    2
#define IDX_FMALL   3
#define IDX_TTHR    4
#define IDX_INVNORM 5
#define IDX_FCNT    6
#define IDX_FMASK   8      /* 256 floats, NATURAL frequency order */
#define IDX_SLOTS   264    /* 64*256 floats, freq-energy partial slots */
#define IDX_AMAXB   16648  /* per-block abs-max (plain stores) */
#define IDX_TMAXB   18696  /* per-block time-energy max */
#define IDX_SUMSQ   20744  /* 65536 floats, per-window time energy (sum x^2) */
#define IDX_TMASKA  86280  /* 65536 floats, time mask */

typedef __attribute__((ext_vector_type(8)))  short bf16x8;
typedef __attribute__((ext_vector_type(16))) float f32x16;

__device__ __forceinline__ float dpp_row_sum16(float x)
{
    x += __int_as_float(__builtin_amdgcn_mov_dpp(__float_as_int(x), 0xB1,  0xF, 0xF, true));
    x += __int_as_float(__builtin_amdgcn_mov_dpp(__float_as_int(x), 0x4E,  0xF, 0xF, true));
    x += __int_as_float(__builtin_amdgcn_mov_dpp(__float_as_int(x), 0x141, 0xF, 0xF, true));
    x += __int_as_float(__builtin_amdgcn_mov_dpp(__float_as_int(x), 0x140, 0xF, 0xF, true));
    return x;
}

__device__ __forceinline__ unsigned short bf16r(float v)   /* f32 -> bf16 RNE */
{
    unsigned u = __float_as_uint(v);
    return (unsigned short)((u + 0x7FFFu + ((u >> 16) & 1u)) >> 16);
}
__device__ __forceinline__ unsigned bfpair(float a, float b)
{
    return (unsigned)bf16r(a) | ((unsigned)bf16r(b) << 16);
}

/* stats + f32->bf16 convert + LDS store for one thread's 8 samples */
__device__ __forceinline__ void do_stage(short (*Ab)[264], const float4 v0, const float4 v1,
                                         int wrow, int scol, float* sumsq_g,
                                         float& amax, float& tmx)
{
    amax = fmaxf(amax, fmaxf(fmaxf(fabsf(v0.x), fabsf(v0.y)),
                             fmaxf(fabsf(v0.z), fabsf(v0.w))));
    amax = fmaxf(amax, fmaxf(fmaxf(fabsf(v1.x), fabsf(v1.y)),
                             fmaxf(fabsf(v1.z), fabsf(v1.w))));
    float ss = v0.x*v0.x + v0.y*v0.y + v0.z*v0.z + v0.w*v0.w
             + v1.x*v1.x + v1.y*v1.y + v1.z*v1.z + v1.w*v1.w;
    ss = dpp_row_sum16(ss);
    ss += __shfl_xor(ss, 16);            /* 32 threads of a window -> full sum */
    if (scol == 0) { sumsq_g[wrow] = ss; tmx = fmaxf(tmx, ss); }
    uint4 u;
    u.x = bfpair(v0.x, v0.y); u.y = bfpair(v0.z, v0.w);
    u.z = bfpair(v1.x, v1.y); u.w = bfpair(v1.z, v1.w);
    *(uint4*)&Ab[wrow][scol * 8] = u;
}

/* ---- K1: MFMA direct-DFT. Y = A*F (cos|sin), col-sumsq fused in regs. -----
   16 waves/block; wave wv owns 32 f-cols (cos if wv<8 else sin, f=32*(wv&7)+c).
   A: 32-window groups staged f32->bf16 in LDS [32][264] (row pad -> b128-optimal).
   A-frag (mfma 32x32x16 A op): lane l -> row l&31, k = 8*(l>>5)+j.
   B-frag = F in 64 VGPRs, computed once per lane via sincos.
   C/D (m74/m101): col=lane&31, rows split over regs+lane-half -> column sumsq
   = per-lane reg-sum + shfl_xor(32). Time stats exact f32 during staging. ---- */
__global__ __launch_bounds__(1024) void k_stats(const float* __restrict__ x,
                                                float* __restrict__ W)
{
    __shared__ short Abuf[2][32][264];   /* 2 x 16.5KB */
    __shared__ float red[1024];
    const int tid  = threadIdx.x;
    const int lane = tid & 63;
    const int wv   = tid >> 6;          /* 0..15 */
    const int hi   = lane >> 5;
    const int col  = lane & 31;
    const int wrow = tid >> 5;          /* staging: window row 0..31 */
    const int scol = tid & 31;          /* staging: 8-sample block 0..31 */

    /* F fragments: F[n][fcol] with n = 16*kc + 8*hi + j ; 64 VGPRs */
    bf16x8 F[16];
    {
        const int f = ((wv & 7) << 5) + col;
        const bool use_sin = (wv >= 8);
#pragma unroll
        for (int kc = 0; kc < 16; ++kc) {
            bf16x8 t;
#pragma unroll
            for (int j = 0; j < 8; ++j) {
                const int n = kc * 16 + hi * 8 + j;
                const int m = (n * f) & 255;
                float s, c;
                __sincosf((float)m * 0.024543692606170f, &s, &c);
                t[j] = (short)bf16r(use_sin ? s : c);
            }
            F[kc] = t;
        }
    }

    const int b = blockIdx.x;
    const float* xb = x + ((size_t)b << 16);       /* block's 256 windows */
    float* sumsq = W + IDX_SUMSQ + (b << 8);
    float amax = 0.f, tmx = 0.f, fsum = 0.f;

    /* prologue: load + stage wgroup 0 */
    float4 v0, v1;
    {
        const float4* p = (const float4*)(xb + tid * 8);
        v0 = p[0]; v1 = p[1];
    }
    do_stage(Abuf[0], v0, v1, wrow, scol, sumsq, amax, tmx);
    __syncthreads();

    int cur = 0;
#pragma unroll 1
    for (int g = 0; g < 8; ++g) {
        if (g < 7) {                      /* prefetch next wgroup under MFMA */
            const float4* p = (const float4*)(xb + (g + 1) * 8192 + tid * 8);
            v0 = p[0]; v1 = p[1];
        }
        f32x16 acc;
#pragma unroll
        for (int r = 0; r < 16; ++r) acc[r] = 0.f;
#pragma unroll
        for (int kc = 0; kc < 16; ++kc) {
            const bf16x8 af = *(const bf16x8*)&Abuf[cur][col][kc * 16 + hi * 8];
            acc = __builtin_amdgcn_mfma_f32_32x32x16_bf16(af, F[kc], acc, 0, 0, 0);
        }
#pragma unroll
        for (int r = 0; r < 16; ++r) fsum += acc[r] * acc[r];
        if (g < 7)
            do_stage(Abuf[cur ^ 1], v0, v1, wrow, scol, sumsq + (g + 1) * 32, amax, tmx);
        __syncthreads();
        cur ^= 1;
    }

    /* freq-energy: combine lane halves (rows), add to distributed slots */
    fsum += __shfl_xor(fsum, 32);
    if (lane < 32)
        atomicAdd(&W[IDX_SLOTS + (size_t)(b & (NSLOTS - 1)) * 256 + ((wv & 7) << 5) + lane],
                  fsum);

    /* block tree-reduce amax / tmx -> plain per-block stores */
    red[tid] = amax; __syncthreads();
    for (int s = 512; s > 0; s >>= 1) {
        if (tid < s) red[tid] = fmaxf(red[tid], red[tid + s]);
        __syncthreads();
    }
    if (tid == 0) W[IDX_AMAXB + b] = red[0];
    __syncthreads();
    red[tid] = tmx; __syncthreads();
    for (int s = 512; s > 0; s >>= 1) {
        if (tid < s) red[tid] = fmaxf(red[tid], red[tid + s]);
        __syncthreads();
    }
    if (tid == 0) W[IDX_TMAXB + b] = red[0];
}

/* ---------------- K2: merged masks pass ------------------------------------ */
__global__ __launch_bounds__(256) void k_post(float* __restrict__ W)
{
    __shared__ float red[256];
    const int tid = threadIdx.x;

    if (blockIdx.x != 0) {
        float tm = 0.f;
#pragma unroll
        for (int k = 0; k < ((NBLK + 255) / 256); ++k)
            tm = fmaxf(tm, W[IDX_TMAXB + k * 256 + tid]);
        red[tid] = tm; __syncthreads();
        for (int s = 128; s > 0; s >>= 1) {
            if (tid < s) red[tid] = fmaxf(red[tid], red[tid + s]);
            __syncthreads();
        }
        const float tthr = 0.05f * red[0];
        __syncthreads();
        const float* sumsq = W + IDX_SUMSQ;
        float* tmask = W + IDX_TMASKA;
        const int base = (blockIdx.x - 1) * 1024 + tid;
        int c = 0;
#pragma unroll
        for (int k = 0; k < 4; k++) {
            const int i = base + k * 256;
            const int mm = (sumsq[i] > tthr) ? 1 : 0;
            c += mm;
            tmask[i] = (float)mm;
        }
        red[tid] = (float)c; __syncthreads();
        for (int s = 128; s > 0; s >>= 1) {
            if (tid < s) red[tid] += red[tid + s];
            __syncthreads();
        }
        if (tid == 0) atomicAdd((int*)W + IDX_TCNT, (int)red[0]);
        return;
    }

    __shared__ float e[256];
    float am = 0.f;
#pragma unroll
    for (int k = 0; k < ((NBLK + 255) / 256); ++k)
        am = fmaxf(am, W[IDX_AMAXB + k * 256 + tid]);
    red[tid] = am; __syncthreads();
    for (int s = 128; s > 0; s >>= 1) {
        if (tid < s) red[tid] = fmaxf(red[tid], red[tid + s]);
        __syncthreads();
    }
    const float amax = red[0];
    __syncthreads();

    float acc = 0.f;
#pragma unroll
    for (int s = 0; s < NSLOTS; s++) acc += W[IDX_SLOTS + s * 256 + tid];
    e[tid] = acc;
    red[tid] = acc; __syncthreads();
    for (int s = 128; s > 0; s >>= 1) {
        if (tid < s) red[tid] = fmaxf(red[tid], red[tid + s]);
        __syncthreads();
    }
    const float fthr = 0.05f * red[0];
    __syncthreads();
    const int my = (acc > fthr) ? 1 : 0;
    red[tid] = (float)my; __syncthreads();
    for (int s = 128; s > 0; s >>= 1) {
        if (tid < s) red[tid] += red[tid + s];
        __syncthreads();
    }
    const int fcnt = (int)red[0];
    __syncthreads();
    float m;
    if (fcnt >= MIN_FREQS) {
        m = (float)my;
    } else {
        int rank = 0;
        for (int j = 0; j < 256; j++) {
            const float ej = e[j];
            if (ej > acc || (ej == acc && j < tid)) rank++;
        }
        m = (rank < MIN_FREQS) ? 1.f : 0.f;
    }
    W[IDX_FMASK + tid] = m;
    red[tid] = m; __syncthreads();
    for (int s = 128; s > 0; s >>= 1) {
        if (tid < s) red[tid] += red[tid + s];
        __syncthreads();
    }
    if (tid == 0) {
        ((int*)W)[IDX_FMALL] = ((int)red[0] == 256) ? 1 : 0;
        ((int*)W)[IDX_FCNT]  = fcnt;
        W[IDX_INVNORM] = 1.f / ((amax > 1e-10f) ? amax : 1.f);
    }
}

/* ---------------- K2b: exact time top-k fallback (early-exit normally) ----- */
__global__ __launch_bounds__(256) void k_timefb(float* __restrict__ W)
{
    if (((const int*)W)[IDX_TCNT] >= MIN_TIMES) return;
    const int t = blockIdx.x * 256 + threadIdx.x;
    const float* sumsq = W + IDX_SUMSQ;
    const float st = sumsq[t];
    int rank = 0;
    for (int j = 0; j < NWIN; j++) {
        const float sj = sumsq[j];
        if (sj > st || (sj == st && j < t)) rank++;
    }
    W[IDX_TMASKA + t] = (rank < MIN_TIMES) ? 1.f : 0.f;
}

/* ---------------- K3: output pass ------------------------------------------ */
__global__ __launch_bounds__(256) void k_out(const float* __restrict__ x,
                                             float* __restrict__ out,
                                             const float* __restrict__ W)
{
    const int tid = threadIdx.x;
    const int fm_all = ((const int*)W)[IDX_FMALL];
    const float inv_norm = W[IDX_INVNORM];
    if (fm_all) {
        const float4* xi = (const float4*)x;
        float4* yo = (float4*)out;
        const float* tmask = W + IDX_TMASKA;
        for (int i = blockIdx.x * 256 + tid; i < N_TOTAL / 4; i += gridDim.x * 256) {
            const float s = inv_norm * tmask[i >> 6];
            float4 v = xi[i];
            v.x *= s; v.y *= s; v.z *= s; v.w *= s;
            yo[i] = v;
        }
        return;
    }
    /* general path: exact FFT -> mask -> IFFT (mask lookup brev for DIF order) */
    __shared__ float re[256], im[256], twr[128], twi[128], fm[256];
    if (tid < 128) {
        float s, c;
        __sincosf(-6.283185307179586f * (float)tid / 256.0f, &s, &c);
        twr[tid] = c; twi[tid] = s;
    }
    fm[tid] = W[IDX_FMASK + (int)(__brev((unsigned)tid) >> 24)];
    __syncthreads();
    const float scale = inv_norm * (1.f / 256.f);
    for (int w = blockIdx.x; w < NWIN; w += gridDim.x) {
        const float tm = W[IDX_TMASKA + w];
        if (tm == 0.f) { out[w * 256 + tid] = 0.f; continue; }
        re[tid] = x[w * 256 + tid]; im[tid] = 0.f;
        __syncthreads();
        for (int lh = 7; lh >= 0; lh--) {
            const int half = 1 << lh;
            if (tid < 128) {
                const int k  = tid & (half - 1);
                const int i0 = ((tid & ~(half - 1)) << 1) | k;
                const int i1 = i0 + half;
                const float ar = re[i0], ai = im[i0], br = re[i1], bi = im[i1];
                const float dr = ar - br, di = ai - bi;
                re[i0] = ar + br; im[i0] = ai + bi;
                const int ti = k << (7 - lh);
                const float wr = twr[ti], wi = twi[ti];
                re[i1] = dr * wr - di * wi;
                im[i1] = dr * wi + di * wr;
            }
            __syncthreads();
        }
        re[tid] *= fm[tid]; im[tid] *= fm[tid];
        __syncthreads();
        for (int lh = 0; lh < 8; lh++) {
            const int half = 1 << lh;
            if (tid < 128) {
                const int k  = tid & (half - 1);
                const int i0 = ((tid & ~(half - 1)) << 1) | k;
                const int i1 = i0 + half;
                const int ti = k << (7 - lh);
                const float wr = twr[ti], wi = -twi[ti];
                const float br = re[i1], bi = im[i1];
                const float tr = br * wr - bi * wi;
                const float ts = br * wi + bi * wr;
                const float ar = re[i0], ai = im[i0];
                re[i1] = ar - tr; im[i1] = ai - ts;
                re[i0] = ar + tr; im[i0] = ai + ts;
            }
            __syncthreads();
        }
        out[w * 256 + tid] = re[tid] * scale;
        __syncthreads();
    }
}

extern "C" void kernel_launch(void* const* d_in, const int* in_sizes, int n_in,
                              void* d_out, int out_size, void* d_ws, size_t ws_size,
                              hipStream_t stream)
{
    const float* x = (const float*)d_in[0];
    float* out = (float*)d_out;
    float* W = (float*)d_ws;
    hipMemsetAsync(d_ws, 0, (size_t)IDX_AMAXB * sizeof(float), stream);
    hipLaunchKernelGGL(k_stats,  dim3(NBLK), dim3(1024), 0, stream, x, W);
    hipLaunchKernelGGL(k_post,   dim3(65),   dim3(256),  0, stream, W);
    hipLaunchKernelGGL(k_timefb, dim3(256),  dim3(256),  0, stream, W);
    hipLaunchKernelGGL(k_out,    dim3(2048), dim3(256),  0, stream, x, out, W);
}